// Round 1
// baseline (163.084 us; speedup 1.0000x reference)
//
#include <hip/hip_runtime.h>
#include <hip/hip_bf16.h>

typedef __attribute__((ext_vector_type(8))) short short8_t;
typedef __attribute__((ext_vector_type(4))) float f32x4;

#define NB 2
#define CC 64
#define RCC 8
#define NN 9216
#define QT 32
#define KBLK 256
#define NKB 36       // NN / KBLK
#define QTILES 288   // NN / QT

static __device__ __forceinline__ unsigned short f2bf(float f) {
    unsigned int u = __builtin_bit_cast(unsigned int, f);
    u += 0x7fffu + ((u >> 16) & 1u);
    return (unsigned short)(u >> 16);
}

// ---------------- projection kernel ----------------
// grid = (B*N/256, 6): y=0..3 -> v channel groups of 16, y=4 -> q, y=5 -> k
__global__ __launch_bounds__(256) void proj_kernel(
    const float* __restrict__ x,
    const float* __restrict__ wq, const float* __restrict__ bq,
    const float* __restrict__ wk, const float* __restrict__ bk,
    const float* __restrict__ wv, const float* __restrict__ bv,
    unsigned short* __restrict__ qbf,   // [B][N][8] bf16 (scale folded)
    unsigned short* __restrict__ kbf,   // [B][N][8] bf16
    unsigned short* __restrict__ vbf)   // [B][C][N] bf16
{
    const int grp = blockIdx.y;
    __shared__ float sw[16 * CC];
    __shared__ float sb[16];
    const int t = threadIdx.x;

    const float* wsrc;
    const float* bsrc;
    int rows;
    if (grp < 4)       { wsrc = wv + grp * 16 * CC; bsrc = bv + grp * 16; rows = 16; }
    else if (grp == 4) { wsrc = wq; bsrc = bq; rows = RCC; }
    else               { wsrc = wk; bsrc = bk; rows = RCC; }
    for (int i = t; i < rows * CC; i += 256) sw[i] = wsrc[i];
    if (t < rows) sb[t] = bsrc[t];
    __syncthreads();

    const int gid = blockIdx.x * 256 + t;   // 0 .. B*N-1 (exact)
    const int b = gid / NN, n = gid % NN;
    const float* xp = x + (size_t)b * CC * NN + n;
    float xv[CC];
    #pragma unroll
    for (int c = 0; c < CC; ++c) xv[c] = xp[(size_t)c * NN];

    if (grp < 4) {
        for (int o = 0; o < 16; ++o) {
            const float4* wr = (const float4*)&sw[o * CC];
            float a = sb[o];
            #pragma unroll
            for (int c4 = 0; c4 < CC / 4; ++c4) {
                float4 wd = wr[c4];
                a += wd.x * xv[4*c4] + wd.y * xv[4*c4+1] + wd.z * xv[4*c4+2] + wd.w * xv[4*c4+3];
            }
            vbf[((size_t)b * CC + grp * 16 + o) * NN + n] = f2bf(a);
        }
    } else {
        const float scale = (grp == 4) ? (1.0f / 96.0f) : 1.0f;
        unsigned short* dst = (grp == 4) ? qbf : kbf;
        union { unsigned short u[8]; uint4 q4; } pk;
        #pragma unroll
        for (int r = 0; r < RCC; ++r) {
            const float4* wr = (const float4*)&sw[r * CC];
            float a = sb[r];
            #pragma unroll
            for (int c4 = 0; c4 < CC / 4; ++c4) {
                float4 wd = wr[c4];
                a += wd.x * xv[4*c4] + wd.y * xv[4*c4+1] + wd.z * xv[4*c4+2] + wd.w * xv[4*c4+3];
            }
            pk.u[r] = f2bf(a * scale);
        }
        *(uint4*)(dst + (size_t)gid * RCC) = pk.q4;
    }
}

// ---------------- attention kernel ----------------
// grid = B*QTILES blocks, 256 threads (4 waves).
// Block: batch b, 32 queries. Wave w: S' for keys [w*64,w*64+64) of each
// 256-key block; PV for channels [16w,16w+16) over all 256 keys.
__global__ __launch_bounds__(256) void attn_kernel(
    const unsigned short* __restrict__ qbf,
    const unsigned short* __restrict__ kbf,
    const unsigned short* __restrict__ vbf,
    const float* __restrict__ x,
    const float* __restrict__ gamma,
    float* __restrict__ out)
{
    constexpr int PSTR = KBLK + 8;          // +8 bf16 pad -> bank spread
    __shared__ unsigned short P[QT][PSTR];  // P[query][key] bf16, unnormalized
    __shared__ float rsum[4][QT];

    const int tid = threadIdx.x;
    const int w  = tid >> 6;
    const int l  = tid & 63;
    const int g  = l >> 4;
    const int li = l & 15;

    const int bid = blockIdx.x;
    const int b = bid / QTILES;
    const int qt = bid % QTILES;
    const int qbase = qt * QT;

    const unsigned short* qb  = qbf + (size_t)b * NN * RCC;
    const unsigned short* kbp = kbf + (size_t)b * NN * RCC;
    const unsigned short* vb  = vbf + (size_t)b * CC * NN;

    // Q as MFMA B-operand (K=32 padded; only k=0..7 real -> lanes g==0)
    short8_t qf0 = {0,0,0,0,0,0,0,0};
    short8_t qf1 = {0,0,0,0,0,0,0,0};
    if (g == 0) {
        qf0 = *(const short8_t*)(qb + (size_t)(qbase + li) * RCC);
        qf1 = *(const short8_t*)(qb + (size_t)(qbase + 16 + li) * RCC);
    }

    const f32x4 zero4 = {0.f, 0.f, 0.f, 0.f};
    f32x4 O0 = zero4, O1 = zero4;
    float rs0 = 0.f, rs1 = 0.f;

    for (int kb = 0; kb < NKB; ++kb) {
        const int key0 = kb * KBLK;
        // ---- S' = K * Q^T, exp, store P ----
        #pragma unroll
        for (int kf = 0; kf < 4; ++kf) {
            const int kcol = w * 64 + kf * 16;   // key offset within block
            short8_t ka = {0,0,0,0,0,0,0,0};
            if (g == 0)
                ka = *(const short8_t*)(kbp + (size_t)(key0 + kcol + li) * RCC);
            f32x4 s0 = __builtin_amdgcn_mfma_f32_16x16x32_bf16(ka, qf0, zero4, 0, 0, 0);
            f32x4 s1 = __builtin_amdgcn_mfma_f32_16x16x32_bf16(ka, qf1, zero4, 0, 0, 0);
            union { unsigned short u[4]; uint2 d; } w0, w1;
            #pragma unroll
            for (int r = 0; r < 4; ++r) {
                float p0 = __expf(s0[r]);
                float p1 = __expf(s1[r]);
                rs0 += p0; rs1 += p1;
                w0.u[r] = f2bf(p0);
                w1.u[r] = f2bf(p1);
            }
            // lane holds keys kcol+4g..kcol+4g+3 for query li (frag0) / 16+li (frag1)
            *(uint2*)&P[li][kcol + 4 * g]      = w0.d;
            *(uint2*)&P[16 + li][kcol + 4 * g] = w1.d;
        }
        __syncthreads();
        // ---- O += V * P ----
        const unsigned short* vp = vb + (size_t)(w * 16 + li) * NN + key0 + 8 * g;
        #pragma unroll
        for (int ks = 0; ks < 8; ++ks) {
            short8_t va = *(const short8_t*)(vp + ks * 32);
            short8_t p0 = *(const short8_t*)&P[li][ks * 32 + 8 * g];
            short8_t p1 = *(const short8_t*)&P[16 + li][ks * 32 + 8 * g];
            O0 = __builtin_amdgcn_mfma_f32_16x16x32_bf16(va, p0, O0, 0, 0, 0);
            O1 = __builtin_amdgcn_mfma_f32_16x16x32_bf16(va, p1, O1, 0, 0, 0);
        }
        __syncthreads();
    }

    // rowsum: reduce across the 4 lane-groups (same query, different keys)
    rs0 += __shfl_xor(rs0, 16, 64);
    rs0 += __shfl_xor(rs0, 32, 64);
    rs1 += __shfl_xor(rs1, 16, 64);
    rs1 += __shfl_xor(rs1, 32, 64);
    if (g == 0) { rsum[w][li] = rs0; rsum[w][16 + li] = rs1; }
    __syncthreads();

    const float inv0 = 1.0f / (rsum[0][li] + rsum[1][li] + rsum[2][li] + rsum[3][li]);
    const float inv1 = 1.0f / (rsum[0][16+li] + rsum[1][16+li] + rsum[2][16+li] + rsum[3][16+li]);
    const float gm = gamma[0];
    #pragma unroll
    for (int r = 0; r < 4; ++r) {
        const int ch = w * 16 + 4 * g + r;
        const size_t i0 = (size_t)b * CC * NN + (size_t)ch * NN + qbase + li;
        out[i0]      = x[i0]      + gm * O0[r] * inv0;
        out[i0 + 16] = x[i0 + 16] + gm * O1[r] * inv1;
    }
}

extern "C" void kernel_launch(void* const* d_in, const int* in_sizes, int n_in,
                              void* d_out, int out_size, void* d_ws, size_t ws_size,
                              hipStream_t stream) {
    const float* x     = (const float*)d_in[0];
    const float* wq    = (const float*)d_in[1];
    const float* bq    = (const float*)d_in[2];
    const float* wk    = (const float*)d_in[3];
    const float* bk    = (const float*)d_in[4];
    const float* wv    = (const float*)d_in[5];
    const float* bv    = (const float*)d_in[6];
    const float* gamma = (const float*)d_in[7];

    unsigned short* qbf = (unsigned short*)d_ws;
    unsigned short* kbf = qbf + (size_t)NB * NN * RCC;
    unsigned short* vbf = kbf + (size_t)NB * NN * RCC;

    proj_kernel<<<dim3((NB * NN) / 256, 6), 256, 0, stream>>>(
        x, wq, bq, wk, bk, wv, bv, qbf, kbf, vbf);
    attn_kernel<<<NB * QTILES, 256, 0, stream>>>(
        qbf, kbf, vbf, x, gamma, (float*)d_out);
}

// Round 2
// 117.857 us; speedup vs baseline: 1.3837x; 1.3837x over previous
//
#include <hip/hip_runtime.h>
#include <hip/hip_bf16.h>

typedef __attribute__((ext_vector_type(8))) short short8_t;
typedef __attribute__((ext_vector_type(4))) float f32x4;

#define NB 2
#define CC 64
#define RCC 8
#define NN 9216
#define QT 32
#define KBLK 256
#define NKB 36       // NN / KBLK
#define QTILES 288   // NN / QT
#define PPART 2080   // 64*32 partial O + 32 rowsums

static __device__ __forceinline__ unsigned short f2bf(float f) {
    unsigned int u = __builtin_bit_cast(unsigned int, f);
    u += 0x7fffu + ((u >> 16) & 1u);
    return (unsigned short)(u >> 16);
}

// ---------------- projection kernel ----------------
__global__ __launch_bounds__(256) void proj_kernel(
    const float* __restrict__ x,
    const float* __restrict__ wq, const float* __restrict__ bq,
    const float* __restrict__ wk, const float* __restrict__ bk,
    const float* __restrict__ wv, const float* __restrict__ bv,
    unsigned short* __restrict__ qbf,   // [B][N][8] bf16 (scale folded)
    unsigned short* __restrict__ kbf,   // [B][N][8] bf16
    unsigned short* __restrict__ vbf)   // [B][C][N] bf16
{
    const int grp = blockIdx.y;
    __shared__ float sw[16 * CC];
    __shared__ float sb[16];
    const int t = threadIdx.x;

    const float* wsrc;
    const float* bsrc;
    int rows;
    if (grp < 4)       { wsrc = wv + grp * 16 * CC; bsrc = bv + grp * 16; rows = 16; }
    else if (grp == 4) { wsrc = wq; bsrc = bq; rows = RCC; }
    else               { wsrc = wk; bsrc = bk; rows = RCC; }
    for (int i = t; i < rows * CC; i += 256) sw[i] = wsrc[i];
    if (t < rows) sb[t] = bsrc[t];
    __syncthreads();

    const int gid = blockIdx.x * 256 + t;   // 0 .. B*N-1 (exact)
    const int b = gid / NN, n = gid % NN;
    const float* xp = x + (size_t)b * CC * NN + n;
    float xv[CC];
    #pragma unroll
    for (int c = 0; c < CC; ++c) xv[c] = xp[(size_t)c * NN];

    if (grp < 4) {
        for (int o = 0; o < 16; ++o) {
            const float4* wr = (const float4*)&sw[o * CC];
            float a = sb[o];
            #pragma unroll
            for (int c4 = 0; c4 < CC / 4; ++c4) {
                float4 wd = wr[c4];
                a += wd.x * xv[4*c4] + wd.y * xv[4*c4+1] + wd.z * xv[4*c4+2] + wd.w * xv[4*c4+3];
            }
            vbf[((size_t)b * CC + grp * 16 + o) * NN + n] = f2bf(a);
        }
    } else {
        const float scale = (grp == 4) ? (1.0f / 96.0f) : 1.0f;
        unsigned short* dst = (grp == 4) ? qbf : kbf;
        union { unsigned short u[8]; uint4 q4; } pk;
        #pragma unroll
        for (int r = 0; r < RCC; ++r) {
            const float4* wr = (const float4*)&sw[r * CC];
            float a = sb[r];
            #pragma unroll
            for (int c4 = 0; c4 < CC / 4; ++c4) {
                float4 wd = wr[c4];
                a += wd.x * xv[4*c4] + wd.y * xv[4*c4+1] + wd.z * xv[4*c4+2] + wd.w * xv[4*c4+3];
            }
            pk.u[r] = f2bf(a * scale);
        }
        *(uint4*)(dst + (size_t)gid * RCC) = pk.q4;
    }
}

// ---------------- attention kernel ----------------
// grid = NB*QTILES*KSPLIT blocks (ks fastest), 256 threads (4 waves).
// Block: batch b, 32 queries, keys [ks*NN/KSPLIT, (ks+1)*NN/KSPLIT).
// If DIRECT (KSPLIT==1): write normalized out incl. residual.
// Else: write f32 partial (64x32 O + 32 rowsums) to pbuf[bid].
template<int KSPLIT, bool DIRECT>
__global__ __launch_bounds__(256) void attn_kernel(
    const unsigned short* __restrict__ qbf,
    const unsigned short* __restrict__ kbf,
    const unsigned short* __restrict__ vbf,
    const float* __restrict__ x,
    const float* __restrict__ gamma,
    float* __restrict__ out,
    float* __restrict__ pbuf)
{
    constexpr int PSTR = KBLK + 8;          // +8 bf16 pad -> bank spread
    constexpr int NKBS = NKB / KSPLIT;
    __shared__ unsigned short P[QT][PSTR];  // P[query][key] bf16, unnormalized
    __shared__ float rsum[4][QT];

    const int tid = threadIdx.x;
    const int w  = tid >> 6;
    const int l  = tid & 63;
    const int g  = l >> 4;
    const int li = l & 15;

    const int bid = blockIdx.x;
    const int ks  = bid % KSPLIT;
    const int qt  = (bid / KSPLIT) % QTILES;
    const int b   = bid / (KSPLIT * QTILES);
    const int qbase = qt * QT;

    const unsigned short* qb  = qbf + (size_t)b * NN * RCC;
    const unsigned short* kbp = kbf + (size_t)b * NN * RCC;
    const unsigned short* vb  = vbf + (size_t)b * CC * NN;

    // Q as MFMA B-operand (K=32 padded; only k=0..7 real -> lanes g==0)
    short8_t qf0 = {0,0,0,0,0,0,0,0};
    short8_t qf1 = {0,0,0,0,0,0,0,0};
    if (g == 0) {
        qf0 = *(const short8_t*)(qb + (size_t)(qbase + li) * RCC);
        qf1 = *(const short8_t*)(qb + (size_t)(qbase + 16 + li) * RCC);
    }

    const f32x4 zero4 = {0.f, 0.f, 0.f, 0.f};
    f32x4 O0 = zero4, O1 = zero4;
    float rs0 = 0.f, rs1 = 0.f;

    for (int kb = ks * NKBS; kb < (ks + 1) * NKBS; ++kb) {
        const int key0 = kb * KBLK;
        // ---- S' = K * Q^T, exp, store P ----
        #pragma unroll
        for (int kf = 0; kf < 4; ++kf) {
            const int kcol = w * 64 + kf * 16;   // key offset within block
            short8_t ka = {0,0,0,0,0,0,0,0};
            if (g == 0)
                ka = *(const short8_t*)(kbp + (size_t)(key0 + kcol + li) * RCC);
            f32x4 s0 = __builtin_amdgcn_mfma_f32_16x16x32_bf16(ka, qf0, zero4, 0, 0, 0);
            f32x4 s1 = __builtin_amdgcn_mfma_f32_16x16x32_bf16(ka, qf1, zero4, 0, 0, 0);
            union { unsigned short u[4]; uint2 d; } w0, w1;
            #pragma unroll
            for (int r = 0; r < 4; ++r) {
                float p0 = __expf(s0[r]);
                float p1 = __expf(s1[r]);
                rs0 += p0; rs1 += p1;
                w0.u[r] = f2bf(p0);
                w1.u[r] = f2bf(p1);
            }
            *(uint2*)&P[li][kcol + 4 * g]      = w0.d;
            *(uint2*)&P[16 + li][kcol + 4 * g] = w1.d;
        }
        __syncthreads();
        // ---- O += V * P ----
        const unsigned short* vp = vb + (size_t)(w * 16 + li) * NN + key0 + 8 * g;
        #pragma unroll
        for (int ksi = 0; ksi < 8; ++ksi) {
            short8_t va = *(const short8_t*)(vp + ksi * 32);
            short8_t p0 = *(const short8_t*)&P[li][ksi * 32 + 8 * g];
            short8_t p1 = *(const short8_t*)&P[16 + li][ksi * 32 + 8 * g];
            O0 = __builtin_amdgcn_mfma_f32_16x16x32_bf16(va, p0, O0, 0, 0, 0);
            O1 = __builtin_amdgcn_mfma_f32_16x16x32_bf16(va, p1, O1, 0, 0, 0);
        }
        __syncthreads();
    }

    // rowsum: reduce across the 4 lane-groups (same query, different keys)
    rs0 += __shfl_xor(rs0, 16, 64);
    rs0 += __shfl_xor(rs0, 32, 64);
    rs1 += __shfl_xor(rs1, 16, 64);
    rs1 += __shfl_xor(rs1, 32, 64);
    if (g == 0) { rsum[w][li] = rs0; rsum[w][16 + li] = rs1; }
    __syncthreads();

    if constexpr (DIRECT) {
        const float inv0 = 1.0f / (rsum[0][li] + rsum[1][li] + rsum[2][li] + rsum[3][li]);
        const float inv1 = 1.0f / (rsum[0][16+li] + rsum[1][16+li] + rsum[2][16+li] + rsum[3][16+li]);
        const float gm = gamma[0];
        #pragma unroll
        for (int r = 0; r < 4; ++r) {
            const int ch = w * 16 + 4 * g + r;
            const size_t i0 = (size_t)b * CC * NN + (size_t)ch * NN + qbase + li;
            out[i0]      = x[i0]      + gm * O0[r] * inv0;
            out[i0 + 16] = x[i0 + 16] + gm * O1[r] * inv1;
        }
    } else {
        float* po = pbuf + (size_t)bid * PPART;
        #pragma unroll
        for (int r = 0; r < 4; ++r) {
            const int ch = w * 16 + 4 * g + r;
            po[ch * QT + li]      = O0[r];
            po[ch * QT + 16 + li] = O1[r];
        }
        if (tid < QT)
            po[2048 + tid] = rsum[0][tid] + rsum[1][tid] + rsum[2][tid] + rsum[3][tid];
    }
}

// ---------------- combine kernel ----------------
// grid = NB*QTILES blocks, 256 threads. Sum KSPLIT partials, normalize,
// residual-add, write out.
template<int KSPLIT>
__global__ __launch_bounds__(256) void combine_kernel(
    const float* __restrict__ pbuf,
    const float* __restrict__ x,
    const float* __restrict__ gamma,
    float* __restrict__ out)
{
    const int bid = blockIdx.x;             // b*QTILES + qt
    const int b = bid / QTILES, qt = bid % QTILES;
    const float* po = pbuf + (size_t)bid * KSPLIT * PPART;
    const int t = threadIdx.x;
    __shared__ float sden[QT];
    if (t < QT) {
        float d = 0.f;
        #pragma unroll
        for (int s = 0; s < KSPLIT; ++s) d += po[s * PPART + 2048 + t];
        sden[t] = 1.0f / d;
    }
    __syncthreads();
    const float gm = gamma[0];
    #pragma unroll
    for (int i = 0; i < 8; ++i) {
        const int idx = t + i * 256;        // 0..2047
        const int ch = idx >> 5, col = idx & 31;
        float o = 0.f;
        #pragma unroll
        for (int s = 0; s < KSPLIT; ++s) o += po[s * PPART + idx];
        const size_t i0 = ((size_t)b * CC + ch) * NN + qt * QT + col;
        out[i0] = x[i0] + gm * o * sden[col];
    }
}

extern "C" void kernel_launch(void* const* d_in, const int* in_sizes, int n_in,
                              void* d_out, int out_size, void* d_ws, size_t ws_size,
                              hipStream_t stream) {
    const float* x     = (const float*)d_in[0];
    const float* wq    = (const float*)d_in[1];
    const float* bq    = (const float*)d_in[2];
    const float* wk    = (const float*)d_in[3];
    const float* bk    = (const float*)d_in[4];
    const float* wv    = (const float*)d_in[5];
    const float* bv    = (const float*)d_in[6];
    const float* gamma = (const float*)d_in[7];
    float* out = (float*)d_out;

    unsigned short* qbf = (unsigned short*)d_ws;
    unsigned short* kbf = qbf + (size_t)NB * NN * RCC;
    unsigned short* vbf = kbf + (size_t)NB * NN * RCC;
    size_t bufbytes = ((size_t)2 * NB * NN * RCC + (size_t)NB * CC * NN) * sizeof(unsigned short);
    size_t poff = (bufbytes + 255) & ~(size_t)255;
    float* pbuf = (float*)((char*)d_ws + poff);
    size_t avail = ws_size > poff ? ws_size - poff : 0;

    proj_kernel<<<dim3((NB * NN) / 256, 6), 256, 0, stream>>>(
        x, wq, bq, wk, bk, wv, bv, qbf, kbf, vbf);

    auto fits = [&](int kspl) {
        return avail >= (size_t)NB * QTILES * kspl * PPART * sizeof(float);
    };

    if (fits(4)) {
        attn_kernel<4, false><<<NB * QTILES * 4, 256, 0, stream>>>(
            qbf, kbf, vbf, x, gamma, out, pbuf);
        combine_kernel<4><<<NB * QTILES, 256, 0, stream>>>(pbuf, x, gamma, out);
    } else if (fits(2)) {
        attn_kernel<2, false><<<NB * QTILES * 2, 256, 0, stream>>>(
            qbf, kbf, vbf, x, gamma, out, pbuf);
        combine_kernel<2><<<NB * QTILES, 256, 0, stream>>>(pbuf, x, gamma, out);
    } else if (fits(1)) {
        attn_kernel<1, false><<<NB * QTILES, 256, 0, stream>>>(
            qbf, kbf, vbf, x, gamma, out, pbuf);
        combine_kernel<1><<<NB * QTILES, 256, 0, stream>>>(pbuf, x, gamma, out);
    } else {
        attn_kernel<1, true><<<NB * QTILES, 256, 0, stream>>>(
            qbf, kbf, vbf, x, gamma, out, pbuf);
    }
}

// Round 3
// 113.035 us; speedup vs baseline: 1.4428x; 1.0427x over previous
//
#include <hip/hip_runtime.h>
#include <hip/hip_bf16.h>

typedef __attribute__((ext_vector_type(8))) short short8_t;
typedef __attribute__((ext_vector_type(4))) float f32x4;

#define NB 2
#define CC 64
#define RCC 8
#define NN 9216
#define QT 64
#define QTILES 144        // NN/QT
#define PPART (QT*CC + QT) // 4160 f32: [64ch][64q] partial O + 64 rowsums

static __device__ __forceinline__ unsigned short f2bf(float f) {
    unsigned int u = __builtin_bit_cast(unsigned int, f);
    u += 0x7fffu + ((u >> 16) & 1u);
    return (unsigned short)(u >> 16);
}

// ---------------- projection kernel ----------------
// grid = (B*N/64, 2), 64 threads. y=0: q + v[0:32); y=1: k + v[32:64).
// q scale folds 1/sqrt(N) AND log2(e) so attn can use exp2 directly.
__global__ __launch_bounds__(64) void proj_kernel(
    const float* __restrict__ x,
    const float* __restrict__ wq, const float* __restrict__ bq,
    const float* __restrict__ wk, const float* __restrict__ bk,
    const float* __restrict__ wv, const float* __restrict__ bv,
    unsigned short* __restrict__ qbf,   // [B][N][8] bf16
    unsigned short* __restrict__ kbf,   // [B][N][8] bf16
    unsigned short* __restrict__ vbf)   // [B][C][N] bf16
{
    const int grp = blockIdx.y;
    __shared__ float sw[40 * CC];
    __shared__ float sb[40];
    const int t = threadIdx.x;

    const float* w8 = grp ? wk : wq;
    const float* b8 = grp ? bk : bq;
    for (int i = t; i < 8 * CC; i += 64) sw[i] = w8[i];
    for (int i = t; i < 32 * CC; i += 64) sw[8 * CC + i] = wv[grp * 32 * CC + i];
    if (t < 8) sb[t] = b8[t];
    else if (t < 40) sb[t] = bv[grp * 32 + (t - 8)];
    __syncthreads();

    const int gid = blockIdx.x * 64 + t;    // 0 .. B*N-1 exact
    const int b = gid / NN, n = gid % NN;
    const float* xp = x + (size_t)b * CC * NN + n;
    float xv[CC];
    #pragma unroll
    for (int c = 0; c < CC; ++c) xv[c] = xp[(size_t)c * NN];

    // q or k (8 outputs, packed 16B store)
    const float scale = grp ? 1.0f : 0.015028073342593369f; // log2e/96
    unsigned short* dst = grp ? kbf : qbf;
    union { unsigned short u[8]; uint4 q4; } pk;
    #pragma unroll
    for (int r = 0; r < RCC; ++r) {
        const float4* wr = (const float4*)&sw[r * CC];
        float a = sb[r];
        #pragma unroll
        for (int c4 = 0; c4 < CC / 4; ++c4) {
            float4 wd = wr[c4];
            a += wd.x * xv[4*c4] + wd.y * xv[4*c4+1] + wd.z * xv[4*c4+2] + wd.w * xv[4*c4+3];
        }
        pk.u[r] = f2bf(a * scale);
    }
    *(uint4*)(dst + (size_t)gid * RCC) = pk.q4;

    // v (32 channels)
    for (int o = 0; o < 32; ++o) {
        const float4* wr = (const float4*)&sw[(8 + o) * CC];
        float a = sb[8 + o];
        #pragma unroll
        for (int c4 = 0; c4 < CC / 4; ++c4) {
            float4 wd = wr[c4];
            a += wd.x * xv[4*c4] + wd.y * xv[4*c4+1] + wd.z * xv[4*c4+2] + wd.w * xv[4*c4+3];
        }
        vbf[((size_t)b * CC + grp * 32 + o) * NN + n] = f2bf(a);
    }
}

// ---------------- attention kernel ----------------
// grid = NB*QTILES*KSPL (ks fastest), 256 threads = 4 waves.
// Block: (b, 64 queries, key-slice). Wave w: keys [slice + w*slice/4, ...),
// ALL 64 channels. No barriers in the main loop: P is wave-private LDS.
template<int KSPL>
__global__ __launch_bounds__(256) void attn_kernel(
    const unsigned short* __restrict__ qbf,
    const unsigned short* __restrict__ kbf,
    const unsigned short* __restrict__ vbf,
    float* __restrict__ pbuf)
{
    __shared__ char smem[32768];
    // main loop: per-wave P tile at smem + w*8192: [64 q-rows][128B keys], XOR-swizzled
    // epilogue (after barrier): sO f32 [4][16][66] @0, rsum f32 [4][64] @16896

    const int tid = threadIdx.x;
    const int w = tid >> 6, l = tid & 63, g = l >> 4, li = l & 15;

    const int bid = blockIdx.x;
    const int ks = bid % KSPL;
    const int qt = (bid / KSPL) % QTILES;
    const int b  = bid / (KSPL * QTILES);
    const int qbase = qt * QT;
    constexpr int KPB = NN / KSPL;       // keys per block
    constexpr int KPW = KPB / 4;         // keys per wave
    constexpr int NCH = KPW / 64;        // 64-key chunks per wave
    const int key_base = ks * KPB + w * KPW;

    const unsigned short* qb = qbf + (size_t)b * NN * RCC;
    const unsigned short* kp = kbf + (size_t)b * NN * RCC;
    const unsigned short* vb = vbf + (size_t)b * CC * NN;

    const short8_t z8 = {0,0,0,0,0,0,0,0};
    short8_t qf[4] = {z8, z8, z8, z8};
    if (g == 0) {
        #pragma unroll
        for (int j = 0; j < 4; ++j)
            qf[j] = *(const short8_t*)(qb + (size_t)(qbase + 16 * j + li) * RCC);
    }

    const f32x4 zero4 = {0.f, 0.f, 0.f, 0.f};
    f32x4 acc[4][4];   // [f = ch/16][j = q/16]
    #pragma unroll
    for (int f = 0; f < 4; ++f)
        #pragma unroll
        for (int j = 0; j < 4; ++j) acc[f][j] = zero4;
    float rs[4] = {0.f, 0.f, 0.f, 0.f};

    char* Pw = smem + w * 8192;
    const int swz = (li & 7) << 4;

    for (int c = 0; c < NCH; ++c) {
        const int k0 = key_base + c * 64;
        // ---- S' = K·Q^T (keys in rows), exp2, pack, wave-private LDS store ----
        #pragma unroll
        for (int kf = 0; kf < 4; ++kf) {
            short8_t ka = z8;
            if (g == 0)
                ka = *(const short8_t*)(kp + (size_t)(k0 + 16 * kf + li) * RCC);
            #pragma unroll
            for (int j = 0; j < 4; ++j) {
                f32x4 s = __builtin_amdgcn_mfma_f32_16x16x32_bf16(ka, qf[j], zero4, 0, 0, 0);
                union { unsigned short u[4]; uint2 d; } pk4;
                #pragma unroll
                for (int r = 0; r < 4; ++r) {
                    float p = __builtin_amdgcn_exp2f(s[r]);
                    rs[j] += p;
                    pk4.u[r] = f2bf(p);
                }
                // row = query 16j+li; keys 16kf+4g+0..3 at byte 32kf+8g (swizzled)
                *(uint2*)(Pw + (16 * j + li) * 128 + ((32 * kf + 8 * g) ^ swz)) = pk4.d;
            }
        }
        // ---- O += V·P (same-wave LDS readback; lgkmcnt ordering, no barrier) ----
        #pragma unroll
        for (int k2 = 0; k2 < 2; ++k2) {
            short8_t pb[4];
            #pragma unroll
            for (int j = 0; j < 4; ++j)
                pb[j] = *(const short8_t*)(Pw + (16 * j + li) * 128 + ((64 * k2 + 16 * g) ^ swz));
            #pragma unroll
            for (int f = 0; f < 4; ++f) {
                short8_t va = *(const short8_t*)(vb + (size_t)(16 * f + li) * NN + k0 + 32 * k2 + 8 * g);
                #pragma unroll
                for (int j = 0; j < 4; ++j)
                    acc[f][j] = __builtin_amdgcn_mfma_f32_16x16x32_bf16(va, pb[j], acc[f][j], 0, 0, 0);
            }
        }
    }

    // ---- rowsums: reduce over lane-groups g ----
    #pragma unroll
    for (int j = 0; j < 4; ++j) {
        rs[j] += __shfl_xor(rs[j], 16, 64);
        rs[j] += __shfl_xor(rs[j], 32, 64);
    }

    __syncthreads();   // all waves done with P region; reuse smem
    float* sO   = (float*)smem;                 // [4][16][66]
    float* rsum = (float*)(smem + 16896);       // [4][64]
    if (g == 0) {
        #pragma unroll
        for (int j = 0; j < 4; ++j) rsum[w * 64 + 16 * j + li] = rs[j];
    }

    // ---- cross-wave O reduce: 4 rounds of slice exchange ----
    float accR[4][4];
    #pragma unroll
    for (int j = 0; j < 4; ++j)
        #pragma unroll
        for (int r = 0; r < 4; ++r) accR[j][r] = 0.f;

    #pragma unroll
    for (int rr = 0; rr < 4; ++rr) {
        const int s = (w + rr) & 3;
        __syncthreads();
        // wave-uniform switch keeps acc indices static (no scratch)
        switch (s) {
#define WR_SLICE(S) \
            { _Pragma("unroll") \
              for (int j = 0; j < 4; ++j) { _Pragma("unroll") \
                for (int r = 0; r < 4; ++r) \
                  sO[((S) * 16 + 4 * g + r) * 66 + 16 * j + li] = acc[S][j][r]; } }
            case 0: WR_SLICE(0); break;
            case 1: WR_SLICE(1); break;
            case 2: WR_SLICE(2); break;
            case 3: WR_SLICE(3); break;
#undef WR_SLICE
        }
        __syncthreads();
        #pragma unroll
        for (int j = 0; j < 4; ++j)
            #pragma unroll
            for (int r = 0; r < 4; ++r)
                accR[j][r] += sO[(w * 16 + 4 * g + r) * 66 + 16 * j + li];
    }

    // ---- write f32 partial to pbuf ----
    float* po = pbuf + (size_t)bid * PPART;
    #pragma unroll
    for (int j = 0; j < 4; ++j)
        #pragma unroll
        for (int r = 0; r < 4; ++r)
            po[(16 * w + 4 * g + r) * QT + 16 * j + li] = accR[j][r];
    if (tid < QT)
        po[CC * QT + tid] = rsum[tid] + rsum[64 + tid] + rsum[128 + tid] + rsum[192 + tid];
}

// ---------------- combine kernel ----------------
template<int KSPL>
__global__ __launch_bounds__(256) void combine_kernel(
    const float* __restrict__ pbuf,
    const float* __restrict__ x,
    const float* __restrict__ gamma,
    float* __restrict__ out)
{
    const int bid = blockIdx.x;             // b*QTILES + qt
    const int b = bid / QTILES, qt = bid % QTILES;
    const float* po = pbuf + (size_t)bid * KSPL * PPART;
    const int t = threadIdx.x;
    __shared__ float sden[QT];
    if (t < QT) {
        float d = 0.f;
        #pragma unroll
        for (int s = 0; s < KSPL; ++s) d += po[s * PPART + CC * QT + t];
        sden[t] = 1.0f / d;
    }
    __syncthreads();
    const float gm = gamma[0];
    #pragma unroll
    for (int i = 0; i < 16; ++i) {
        const int idx = t + i * 256;        // 0..4095
        const int ch = idx >> 6, col = idx & 63;
        float o = 0.f;
        #pragma unroll
        for (int s = 0; s < KSPL; ++s) o += po[s * PPART + idx];
        const size_t i0 = ((size_t)b * CC + ch) * NN + qt * QT + col;
        out[i0] = x[i0] + gm * o * sden[col];
    }
}

extern "C" void kernel_launch(void* const* d_in, const int* in_sizes, int n_in,
                              void* d_out, int out_size, void* d_ws, size_t ws_size,
                              hipStream_t stream) {
    const float* x     = (const float*)d_in[0];
    const float* wq    = (const float*)d_in[1];
    const float* bq    = (const float*)d_in[2];
    const float* wk    = (const float*)d_in[3];
    const float* bk    = (const float*)d_in[4];
    const float* wv    = (const float*)d_in[5];
    const float* bv    = (const float*)d_in[6];
    const float* gamma = (const float*)d_in[7];
    float* out = (float*)d_out;

    unsigned short* qbf = (unsigned short*)d_ws;
    unsigned short* kbf = qbf + (size_t)NB * NN * RCC;
    unsigned short* vbf = kbf + (size_t)NB * NN * RCC;
    size_t bufbytes = ((size_t)2 * NB * NN * RCC + (size_t)NB * CC * NN) * sizeof(unsigned short);
    size_t poff = (bufbytes + 255) & ~(size_t)255;
    float* pbuf = (float*)((char*)d_ws + poff);
    size_t avail = ws_size > poff ? ws_size - poff : 0;

    proj_kernel<<<dim3((NB * NN) / 64, 2), 64, 0, stream>>>(
        x, wq, bq, wk, bk, wv, bv, qbf, kbf, vbf);

    auto fits = [&](int kspl) {
        return avail >= (size_t)NB * QTILES * kspl * PPART * sizeof(float);
    };

    if (fits(4)) {
        attn_kernel<4><<<NB * QTILES * 4, 256, 0, stream>>>(qbf, kbf, vbf, pbuf);
        combine_kernel<4><<<NB * QTILES, 256, 0, stream>>>(pbuf, x, gamma, out);
    } else if (fits(2)) {
        attn_kernel<2><<<NB * QTILES * 2, 256, 0, stream>>>(qbf, kbf, vbf, pbuf);
        combine_kernel<2><<<NB * QTILES, 256, 0, stream>>>(pbuf, x, gamma, out);
    } else {
        attn_kernel<1><<<NB * QTILES, 256, 0, stream>>>(qbf, kbf, vbf, pbuf);
        combine_kernel<1><<<NB * QTILES, 256, 0, stream>>>(pbuf, x, gamma, out);
    }
}

// Round 4
// 99.165 us; speedup vs baseline: 1.6446x; 1.1399x over previous
//
#include <hip/hip_runtime.h>
#include <hip/hip_bf16.h>

typedef __attribute__((ext_vector_type(8))) short short8_t;
typedef __attribute__((ext_vector_type(4))) float f32x4;

#define NB 2
#define CC 64
#define RCC 8
#define NN 9216
#define QT 64
#define QTILES 144         // NN/QT
#define PPART (QT*CC + QT) // 4160 f32: [64ch][64q] partial O + 64 rowsums

static __device__ __forceinline__ unsigned short f2bf(float f) {
    unsigned int u = __builtin_bit_cast(unsigned int, f);
    u += 0x7fffu + ((u >> 16) & 1u);
    return (unsigned short)(u >> 16);
}
static __device__ __forceinline__ unsigned int bfpack2(float lo, float hi) {
    // bf16(lo) | bf16(hi)<<16, round-half-up via +0x8000, one v_perm_b32
    unsigned int a = __builtin_bit_cast(unsigned int, hi) + 0x8000u;
    unsigned int b = __builtin_bit_cast(unsigned int, lo) + 0x8000u;
    return __builtin_amdgcn_perm(a, b, 0x07060302u);
}

// ---------------- projection kernel ----------------
// grid = (B*N/64, 2), 64 threads. y=0: q + v[0:32); y=1: k + v[32:64).
// q scale folds 1/sqrt(N), log2(e), and 1/4 (replicate-x4 MFMA trick).
__global__ __launch_bounds__(64) void proj_kernel(
    const float* __restrict__ x,
    const float* __restrict__ wq, const float* __restrict__ bq,
    const float* __restrict__ wk, const float* __restrict__ bk,
    const float* __restrict__ wv, const float* __restrict__ bv,
    unsigned short* __restrict__ qbf,   // [B][N][8] bf16
    unsigned short* __restrict__ kbf,   // [B][N][8] bf16
    unsigned short* __restrict__ vbf)   // [B][C][N] bf16
{
    const int grp = blockIdx.y;
    __shared__ float sw[40 * CC];
    __shared__ float sb[40];
    const int t = threadIdx.x;

    const float* w8 = grp ? wk : wq;
    const float* b8 = grp ? bk : bq;
    for (int i = t; i < 8 * CC; i += 64) sw[i] = w8[i];
    for (int i = t; i < 32 * CC; i += 64) sw[8 * CC + i] = wv[grp * 32 * CC + i];
    if (t < 8) sb[t] = b8[t];
    else if (t < 40) sb[t] = bv[grp * 32 + (t - 8)];
    __syncthreads();

    const int gid = blockIdx.x * 64 + t;    // 0 .. B*N-1 exact
    const int b = gid / NN, n = gid % NN;
    const float* xp = x + (size_t)b * CC * NN + n;
    float xv[CC];
    #pragma unroll
    for (int c = 0; c < CC; ++c) xv[c] = xp[(size_t)c * NN];

    // q or k (8 outputs, packed 16B store)
    const float scale = grp ? 1.0f : 0.0037570183356483423f; // log2e/(96*4)
    unsigned short* dst = grp ? kbf : qbf;
    union { unsigned short u[8]; uint4 q4; } pk;
    #pragma unroll
    for (int r = 0; r < RCC; ++r) {
        const float4* wr = (const float4*)&sw[r * CC];
        float a = sb[r];
        #pragma unroll
        for (int c4 = 0; c4 < CC / 4; ++c4) {
            float4 wd = wr[c4];
            a += wd.x * xv[4*c4] + wd.y * xv[4*c4+1] + wd.z * xv[4*c4+2] + wd.w * xv[4*c4+3];
        }
        pk.u[r] = f2bf(a * scale);
    }
    *(uint4*)(dst + (size_t)gid * RCC) = pk.q4;

    // v (32 channels)
    for (int o = 0; o < 32; ++o) {
        const float4* wr = (const float4*)&sw[(8 + o) * CC];
        float a = sb[8 + o];
        #pragma unroll
        for (int c4 = 0; c4 < CC / 4; ++c4) {
            float4 wd = wr[c4];
            a += wd.x * xv[4*c4] + wd.y * xv[4*c4+1] + wd.z * xv[4*c4+2] + wd.w * xv[4*c4+3];
        }
        vbf[((size_t)b * CC + grp * 32 + o) * NN + n] = f2bf(a);
    }
}

// ---------------- attention kernel ----------------
// grid = NB*QTILES*KSPL (ks fastest), 256 threads = 4 waves.
// Wave w: keys [key_base, key_base+KPW), all 64 channels, 32-key chunks.
// Per-j (16 q-rows) P tile, 80B-padded rows, j-parity double buffer,
// wave-private (no barriers in main loop).
template<int KSPL>
__global__ __launch_bounds__(256) void attn_kernel(
    const unsigned short* __restrict__ qbf,
    const unsigned short* __restrict__ kbf,
    const unsigned short* __restrict__ vbf,
    float* __restrict__ pbuf)
{
    __shared__ char smem[17920];
    // main loop: wave w uses smem + w*2560 (2 x 16 rows x 80B)
    // epilogue: sO f32 [4][16][66] @0 (16896B), rsum f32 [4][64] @16896

    const int tid = threadIdx.x;
    const int w = tid >> 6, l = tid & 63, g = l >> 4, li = l & 15;

    const int bid = blockIdx.x;
    const int ks = bid % KSPL;
    const int qt = (bid / KSPL) % QTILES;
    const int b  = bid / (KSPL * QTILES);
    const int qbase = qt * QT;
    constexpr int KPB = NN / KSPL;       // keys per block
    constexpr int KPW = KPB / 4;         // keys per wave
    constexpr int NCH = KPW / 32;        // 32-key chunks per wave
    const int key_base = ks * KPB + w * KPW;

    const unsigned short* qb = qbf + (size_t)b * NN * RCC;
    const unsigned short* kp = kbf + (size_t)b * NN * RCC;
    const unsigned short* vb = vbf + (size_t)b * CC * NN;

    // Q fragments, replicated across g (all lanes load; x4 folded in scale)
    short8_t qf[4];
    #pragma unroll
    for (int j = 0; j < 4; ++j)
        qf[j] = *(const short8_t*)(qb + (size_t)(qbase + 16 * j + li) * RCC);

    const f32x4 zero4 = {0.f, 0.f, 0.f, 0.f};
    f32x4 acc[4][4];   // [f = ch/16][j = q/16]
    #pragma unroll
    for (int f = 0; f < 4; ++f)
        #pragma unroll
        for (int j = 0; j < 4; ++j) acc[f][j] = zero4;
    float rs[4] = {0.f, 0.f, 0.f, 0.f};

    char* Pw = smem + w * 2560;

    for (int c = 0; c < NCH; ++c) {
        const int k0 = key_base + c * 32;
        // prefetch K rows (replicated across g) and V fragments
        short8_t ka0 = *(const short8_t*)(kp + (size_t)(k0 + li) * RCC);
        short8_t ka1 = *(const short8_t*)(kp + (size_t)(k0 + 16 + li) * RCC);
        short8_t va[4];
        #pragma unroll
        for (int f = 0; f < 4; ++f)
            va[f] = *(const short8_t*)(vb + (size_t)(16 * f + li) * NN + k0 + 8 * g);

        #pragma unroll
        for (int j = 0; j < 4; ++j) {
            char* Pj = Pw + (j & 1) * 1280;
            // S' = K*Q^T for 32 keys x 16 queries (result x4, folded)
            f32x4 s0 = __builtin_amdgcn_mfma_f32_16x16x32_bf16(ka0, qf[j], zero4, 0, 0, 0);
            f32x4 s1 = __builtin_amdgcn_mfma_f32_16x16x32_bf16(ka1, qf[j], zero4, 0, 0, 0);
            // exp2 + pack + rowsum (tree)
            float p0 = __builtin_amdgcn_exp2f(s0[0]);
            float p1 = __builtin_amdgcn_exp2f(s0[1]);
            float p2 = __builtin_amdgcn_exp2f(s0[2]);
            float p3 = __builtin_amdgcn_exp2f(s0[3]);
            float p4 = __builtin_amdgcn_exp2f(s1[0]);
            float p5 = __builtin_amdgcn_exp2f(s1[1]);
            float p6 = __builtin_amdgcn_exp2f(s1[2]);
            float p7 = __builtin_amdgcn_exp2f(s1[3]);
            rs[j] += ((p0 + p1) + (p2 + p3)) + ((p4 + p5) + (p6 + p7));
            union { unsigned int u[2]; uint2 d; } w0, w1;
            w0.u[0] = bfpack2(p0, p1); w0.u[1] = bfpack2(p2, p3);
            w1.u[0] = bfpack2(p4, p5); w1.u[1] = bfpack2(p6, p7);
            // row = li (80B), kf0 keys 4g+r at byte 8g; kf1 at 32+8g
            *(uint2*)(Pj + li * 80 + 8 * g)      = w0.d;
            *(uint2*)(Pj + li * 80 + 32 + 8 * g) = w1.d;
            // PV: read 8 keys per lane (16B at byte 16g), 4 MFMA
            short8_t pb = *(const short8_t*)(Pj + li * 80 + 16 * g);
            #pragma unroll
            for (int f = 0; f < 4; ++f)
                acc[f][j] = __builtin_amdgcn_mfma_f32_16x16x32_bf16(va[f], pb, acc[f][j], 0, 0, 0);
        }
    }

    // ---- rowsums: reduce over lane-groups g ----
    #pragma unroll
    for (int j = 0; j < 4; ++j) {
        rs[j] += __shfl_xor(rs[j], 16, 64);
        rs[j] += __shfl_xor(rs[j], 32, 64);
    }

    __syncthreads();   // all waves done with P region; reuse smem
    float* sO   = (float*)smem;                 // [4][16][66]
    float* rsum = (float*)(smem + 16896);       // [4][64]
    if (g == 0) {
        #pragma unroll
        for (int j = 0; j < 4; ++j) rsum[w * 64 + 16 * j + li] = rs[j];
    }

    // ---- cross-wave O reduce: 4 rounds of slice exchange ----
    float accR[4][4];
    #pragma unroll
    for (int j = 0; j < 4; ++j)
        #pragma unroll
        for (int r = 0; r < 4; ++r) accR[j][r] = 0.f;

    #pragma unroll
    for (int rr = 0; rr < 4; ++rr) {
        const int s = (w + rr) & 3;
        __syncthreads();
        switch (s) {
#define WR_SLICE(S) \
            { _Pragma("unroll") \
              for (int j = 0; j < 4; ++j) { _Pragma("unroll") \
                for (int r = 0; r < 4; ++r) \
                  sO[((S) * 16 + 4 * g + r) * 66 + 16 * j + li] = acc[S][j][r]; } }
            case 0: WR_SLICE(0); break;
            case 1: WR_SLICE(1); break;
            case 2: WR_SLICE(2); break;
            case 3: WR_SLICE(3); break;
#undef WR_SLICE
        }
        __syncthreads();
        #pragma unroll
        for (int j = 0; j < 4; ++j)
            #pragma unroll
            for (int r = 0; r < 4; ++r)
                accR[j][r] += sO[(w * 16 + 4 * g + r) * 66 + 16 * j + li];
    }

    // ---- write f32 partial to pbuf ----
    float* po = pbuf + (size_t)bid * PPART;
    #pragma unroll
    for (int j = 0; j < 4; ++j)
        #pragma unroll
        for (int r = 0; r < 4; ++r)
            po[(16 * w + 4 * g + r) * QT + 16 * j + li] = accR[j][r];
    if (tid < QT)
        po[CC * QT + tid] = rsum[tid] + rsum[64 + tid] + rsum[128 + tid] + rsum[192 + tid];
}

// ---------------- combine kernel ----------------
template<int KSPL>
__global__ __launch_bounds__(256) void combine_kernel(
    const float* __restrict__ pbuf,
    const float* __restrict__ x,
    const float* __restrict__ gamma,
    float* __restrict__ out)
{
    const int bid = blockIdx.x;             // b*QTILES + qt
    const int b = bid / QTILES, qt = bid % QTILES;
    const float* po = pbuf + (size_t)bid * KSPL * PPART;
    const int t = threadIdx.x;
    __shared__ float sden[QT];
    if (t < QT) {
        float d = 0.f;
        #pragma unroll
        for (int s = 0; s < KSPL; ++s) d += po[s * PPART + CC * QT + t];
        sden[t] = 1.0f / d;
    }
    __syncthreads();
    const float gm = gamma[0];
    #pragma unroll
    for (int i = 0; i < 16; ++i) {
        const int idx = t + i * 256;        // 0..4095
        const int ch = idx >> 6, col = idx & 63;
        float o = 0.f;
        #pragma unroll
        for (int s = 0; s < KSPL; ++s) o += po[s * PPART + idx];
        const size_t i0 = ((size_t)b * CC + ch) * NN + qt * QT + col;
        out[i0] = x[i0] + gm * o * sden[col];
    }
}

extern "C" void kernel_launch(void* const* d_in, const int* in_sizes, int n_in,
                              void* d_out, int out_size, void* d_ws, size_t ws_size,
                              hipStream_t stream) {
    const float* x     = (const float*)d_in[0];
    const float* wq    = (const float*)d_in[1];
    const float* bq    = (const float*)d_in[2];
    const float* wk    = (const float*)d_in[3];
    const float* bk    = (const float*)d_in[4];
    const float* wv    = (const float*)d_in[5];
    const float* bv    = (const float*)d_in[6];
    const float* gamma = (const float*)d_in[7];
    float* out = (float*)d_out;

    unsigned short* qbf = (unsigned short*)d_ws;
    unsigned short* kbf = qbf + (size_t)NB * NN * RCC;
    unsigned short* vbf = kbf + (size_t)NB * NN * RCC;
    size_t bufbytes = ((size_t)2 * NB * NN * RCC + (size_t)NB * CC * NN) * sizeof(unsigned short);
    size_t poff = (bufbytes + 255) & ~(size_t)255;
    float* pbuf = (float*)((char*)d_ws + poff);
    size_t avail = ws_size > poff ? ws_size - poff : 0;

    proj_kernel<<<dim3((NB * NN) / 64, 2), 64, 0, stream>>>(
        x, wq, bq, wk, bk, wv, bv, qbf, kbf, vbf);

    auto fits = [&](int kspl) {
        return avail >= (size_t)NB * QTILES * kspl * PPART * sizeof(float);
    };

    if (fits(8)) {
        attn_kernel<8><<<NB * QTILES * 8, 256, 0, stream>>>(qbf, kbf, vbf, pbuf);
        combine_kernel<8><<<NB * QTILES, 256, 0, stream>>>(pbuf, x, gamma, out);
    } else if (fits(4)) {
        attn_kernel<4><<<NB * QTILES * 4, 256, 0, stream>>>(qbf, kbf, vbf, pbuf);
        combine_kernel<4><<<NB * QTILES, 256, 0, stream>>>(pbuf, x, gamma, out);
    } else if (fits(2)) {
        attn_kernel<2><<<NB * QTILES * 2, 256, 0, stream>>>(qbf, kbf, vbf, pbuf);
        combine_kernel<2><<<NB * QTILES, 256, 0, stream>>>(pbuf, x, gamma, out);
    } else {
        attn_kernel<1><<<NB * QTILES, 256, 0, stream>>>(qbf, kbf, vbf, pbuf);
        combine_kernel<1><<<NB * QTILES, 256, 0, stream>>>(pbuf, x, gamma, out);
    }
}